// Round 3
// baseline (841.237 us; speedup 1.0000x reference)
//
#include <hip/hip_runtime.h>
#include <hip/hip_bf16.h>
#include <stdint.h>

// Problem constants
#define B_  2
#define S_  2048
#define H_  4096
#define NQ_ 32
#define NKV_ 8
#define D_  128
#define NQKV_ 6144   // (NQ+2*NKV)*D

typedef __bf16 bf16_t;
typedef __bf16 bf16x4 __attribute__((ext_vector_type(4)));
typedef __bf16 bf16x8 __attribute__((ext_vector_type(8)));
typedef float  floatx4 __attribute__((ext_vector_type(4)));

#define GLOBAL_AS __attribute__((address_space(1)))
#define LDS_AS    __attribute__((address_space(3)))

// Softmax scale folded into Q at RoPE time: 1/sqrt(128) * log2(e)
#define QSCALE (0.08838834764831845f * 1.4426950408889634f)

// ---------------------------------------------------------------------------
// f32 -> bf16 elementwise convert (vectorized: 4 elems/thread)
// ---------------------------------------------------------------------------
__global__ __launch_bounds__(256) void convert_f32_bf16(
    const float* __restrict__ src, bf16_t* __restrict__ dst, int n4) {
  int i = blockIdx.x * 256 + threadIdx.x;
  if (i < n4) {
    float4 v = ((const float4*)src)[i];
    bf16_t o[4] = {(bf16_t)v.x, (bf16_t)v.y, (bf16_t)v.z, (bf16_t)v.w};
    ((uint64_t*)dst)[i] = *(const uint64_t*)o;
  }
}

// ---------------------------------------------------------------------------
// Transpose + convert: src f32 [R][C] -> dst bf16 [C][R], 64x64 LDS tiles
// ---------------------------------------------------------------------------
__global__ __launch_bounds__(256) void transpose_f32_bf16(
    const float* __restrict__ src, bf16_t* __restrict__ dst, int R, int C) {
  __shared__ bf16_t tile[64][65];
  const int ct = blockIdx.x * 64, rt = blockIdx.y * 64;
  const int t = threadIdx.x;
  const int cl = t & 63;
  for (int i = 0; i < 16; ++i) {
    int rl = i * 4 + (t >> 6);
    tile[rl][cl] = (bf16_t)src[(size_t)(rt + rl) * C + ct + cl];
  }
  __syncthreads();
  const int rl2 = t & 63;
  for (int i = 0; i < 16; ++i) {
    int cl2 = i * 4 + (t >> 6);
    dst[(size_t)(ct + cl2) * R + rt + rl2] = tile[rl2][cl2];
  }
}

// ---------------------------------------------------------------------------
// GEMM 256x256: C[M,N] = A[M,K] * Bt[N,K]^T  (bf16 in, OutT out, fp32 accum)
// 8-wave 256^2 tile, BK=64, double-buffered LDS (128 KiB), 4 phases/K-tile.
// Phase p computes one block-level 128x128 C-quadrant (one A-half x one
// B-half, 16 MFMA/wave) and stages exactly one half-tile of K-tile t+1 into
// the dead buffer. Counted vmcnt(4) per phase (never 0 in main loop), one
// s_barrier per phase, sched_barrier(0) pins, setprio around MFMA,
// XOR-swizzled LDS with pre-swizzled global source, XCD-aware block swizzle.
// Requires M%256==0, N%256==0, K%64==0, nwg%8==0.
// ---------------------------------------------------------------------------
template <typename OutT>
__global__ __launch_bounds__(512, 2) void gemm_abt256(
    const bf16_t* __restrict__ A, const bf16_t* __restrict__ Bt,
    OutT* __restrict__ C, int M, int N, int K) {
  __shared__ __align__(16) char lds[131072];  // 2 bufs x (A 32K + B 32K)

  const int nbx = gridDim.x;
  const int nwg = nbx * gridDim.y;
  int bid = blockIdx.y * nbx + blockIdx.x;
  bid = (bid & 7) * (nwg >> 3) + (bid >> 3);
  const int bx = bid % nbx, by = bid / nbx;

  const int tid = threadIdx.x;               // 0..511
  const int wave = tid >> 6, lane = tid & 63;
  const int lrow = lane & 15, quad = lane >> 4;
  const int wr = wave >> 2, wc = wave & 3;   // wave pos inside a quadrant
  const int row0 = by * 256, col0 = bx * 256;

  // Staging: one half = 128 rows x 64 cols bf16 = 16 KB = 2 issues x 8 KB.
  // Issue i: wave w writes linear 1 KB at dst + i*8192 + w*1024;
  // lane -> row i*64 + w*8 + (lane>>3), linear colByte (lane&7)*16;
  // global source col pre-swizzled by (row&7)<<4 (row&7 == lane>>3).
  const int lr = lane >> 3;
  const int lc = ((((lane & 7) << 4) ^ (lr << 4)) >> 1);  // elem col

  auto stageHalf = [&](char* dst, const bf16_t* src, int grow, int kt) {
#pragma unroll
    for (int i = 0; i < 2; ++i) {
      const bf16_t* g =
          src + (size_t)(grow + i * 64 + wave * 8 + lr) * K + kt + lc;
      __builtin_amdgcn_global_load_lds((GLOBAL_AS void*)g,
          (LDS_AS void*)(dst + i * 8192 + wave * 1024), 16, 0, 0);
    }
  };

  floatx4 acc[2][2][4][2] = {};  // [mh][nh][fm][fn]
  const int nt = K >> 6;
  const int sw = (lrow & 7) << 4;  // read-side swizzle

// Compute one 128x128 C-quadrant (MH, NH) over K=64 (16 MFMA/wave).
#define PHASE_COMPUTE(MH, NH)                                               \
  {                                                                         \
    bf16x8 af[4][2], bfr[2][2];                                             \
    _Pragma("unroll") for (int fm = 0; fm < 4; ++fm) {                      \
      const int rh = wr * 64 + fm * 16 + lrow;                              \
      _Pragma("unroll") for (int kk = 0; kk < 2; ++kk)                      \
        af[fm][kk] = *(const bf16x8*)(aB + (MH) * 16384 + rh * 128 +        \
                                      ((kk * 64 + quad * 16) ^ sw));        \
    }                                                                       \
    _Pragma("unroll") for (int fn = 0; fn < 2; ++fn) {                      \
      const int rb = wc * 32 + fn * 16 + lrow;                              \
      _Pragma("unroll") for (int kk = 0; kk < 2; ++kk)                      \
        bfr[fn][kk] = *(const bf16x8*)(bB + (NH) * 16384 + rb * 128 +       \
                                       ((kk * 64 + quad * 16) ^ sw));       \
    }                                                                       \
    __builtin_amdgcn_s_setprio(1);                                          \
    _Pragma("unroll") for (int kk = 0; kk < 2; ++kk)                        \
      _Pragma("unroll") for (int fm = 0; fm < 4; ++fm)                      \
        _Pragma("unroll") for (int fn = 0; fn < 2; ++fn)                    \
          acc[MH][NH][fm][fn] = __builtin_amdgcn_mfma_f32_16x16x32_bf16(    \
              af[fm][kk], bfr[fn][kk], acc[MH][NH][fm][fn], 0, 0, 0);       \
    __builtin_amdgcn_s_setprio(0);                                          \
  }

#define PIN() __builtin_amdgcn_sched_barrier(0)

  // Prologue: tile 0, halves in consumption order A0, B0, A1, B1.
  stageHalf(lds + 0,     A,  row0,       0);
  stageHalf(lds + 32768, Bt, col0,       0);
  stageHalf(lds + 16384, A,  row0 + 128, 0);
  stageHalf(lds + 49152, Bt, col0 + 128, 0);

  for (int t = 0; t < nt; ++t) {
    const int cur = t & 1;
    const char* aB = lds + cur * 65536;
    const char* bB = aB + 32768;
    char* aS = lds + (cur ^ 1) * 65536;
    char* bS = aS + 32768;
    const int kt1 = (t + 1) * 64;
    const bool pf = (t + 1 < nt);  // block-uniform

    // phase 0: quadrant (0,0); needs A0,B0 of t; stage A0(t+1)
    PIN();
    asm volatile("s_waitcnt vmcnt(4)" ::: "memory");
    PIN();
    __builtin_amdgcn_s_barrier();
    PIN();
    if (pf) stageHalf(aS, A, row0, kt1);
    PHASE_COMPUTE(0, 0)

    // phase 1: quadrant (1,0); needs A1 of t; stage B0(t+1)
    PIN();
    if (pf) asm volatile("s_waitcnt vmcnt(4)" ::: "memory");
    else    asm volatile("s_waitcnt vmcnt(2)" ::: "memory");
    PIN();
    __builtin_amdgcn_s_barrier();
    PIN();
    if (pf) stageHalf(bS, Bt, col0, kt1);
    PHASE_COMPUTE(1, 0)

    // phase 2: quadrant (1,1); needs B1 of t; stage A1(t+1)
    PIN();
    if (pf) asm volatile("s_waitcnt vmcnt(4)" ::: "memory");
    else    asm volatile("s_waitcnt vmcnt(0)" ::: "memory");
    PIN();
    __builtin_amdgcn_s_barrier();
    PIN();
    if (pf) stageHalf(aS + 16384, A, row0 + 128, kt1);
    PHASE_COMPUTE(0, 1)

    // phase 3: quadrant (0,1); needs nothing new; stage B1(t+1)
    PIN();
    __builtin_amdgcn_s_barrier();
    PIN();
    if (pf) stageHalf(bS + 16384, Bt, col0 + 128, kt1);
    PHASE_COMPUTE(1, 1)
  }

  // epilogue: C/D layout col=lane&15, row=quad*4+reg
#pragma unroll
  for (int mh = 0; mh < 2; ++mh)
#pragma unroll
    for (int nh = 0; nh < 2; ++nh)
#pragma unroll
      for (int fm = 0; fm < 4; ++fm)
#pragma unroll
        for (int fn = 0; fn < 2; ++fn)
#pragma unroll
          for (int r = 0; r < 4; ++r) {
            int row = row0 + mh * 128 + wr * 64 + fm * 16 + quad * 4 + r;
            int col = col0 + nh * 128 + wc * 32 + fn * 16 + lrow;
            C[(size_t)row * N + col] = (OutT)acc[mh][nh][fm][fn][r];
          }
#undef PHASE_COMPUTE
#undef PIN
}

// ---------------------------------------------------------------------------
// RoPE (GPT-J interleaved) on q,k + layout transform
// qkv[B*S][6144] -> Q[B][NQ][S][D], K[B][NKV][S][D]
// Q additionally pre-scaled by 1/sqrt(D)*log2(e) so flash_attn can use
// exp2 directly with no per-score multiplies.
// ---------------------------------------------------------------------------
__global__ __launch_bounds__(256) void rope_qk(
    const bf16_t* __restrict__ qkv, const int* __restrict__ positions,
    bf16_t* __restrict__ Q, bf16_t* __restrict__ K) {
  const int row = blockIdx.x;                 // b*S + s
  const int b = row >> 11, s = row & (S_ - 1);
  const float pos = (float)positions[row];
  const bf16_t* src = qkv + (size_t)row * NQKV_;
  for (int p = threadIdx.x; p < (NQ_ + NKV_) * 64; p += 256) {
    const int head = p >> 6, i = p & 63;
    const float inv = __powf(10000.0f, -(float)i * (1.0f / 64.0f));
    const float f = pos * inv;
    const float cs = __cosf(f), sn = __sinf(f);
    const float x1 = (float)src[head * 128 + 2 * i];
    const float x2 = (float)src[head * 128 + 2 * i + 1];
    float o1 = x1 * cs - x2 * sn;
    float o2 = x2 * cs + x1 * sn;
    bf16_t* dst;
    if (head < NQ_) {
      o1 *= QSCALE;
      o2 *= QSCALE;
      dst = Q + ((size_t)(b * NQ_ + head) * S_ + s) * D_ + 2 * i;
    } else {
      dst = K + ((size_t)(b * NKV_ + (head - NQ_)) * S_ + s) * D_ + 2 * i;
    }
    dst[0] = (bf16_t)o1;
    dst[1] = (bf16_t)o2;
  }
}

// ---------------------------------------------------------------------------
// Extract V from qkv and transpose: qkv cols [5120,6144) -> Vt[B][NKV][D][S]
// ---------------------------------------------------------------------------
__global__ __launch_bounds__(256) void v_transpose(
    const bf16_t* __restrict__ qkv, bf16_t* __restrict__ Vt) {
  __shared__ bf16_t tile[64][65];
  const int b = blockIdx.z;
  const int kh = blockIdx.y >> 1;
  const int dt = (blockIdx.y & 1) * 64;
  const int st = blockIdx.x * 64;
  const int t = threadIdx.x;
  const int colbase = (NQ_ + NKV_) * D_ + kh * D_ + dt;  // 5120 + ...
  for (int i = 0; i < 16; ++i) {
    int sl = i * 4 + (t >> 6);
    int dl = t & 63;
    tile[sl][dl] = qkv[(size_t)(b * S_ + st + sl) * NQKV_ + colbase + dl];
  }
  __syncthreads();
  for (int i = 0; i < 16; ++i) {
    int dl = i * 4 + (t >> 6);
    int sl = t & 63;
    Vt[((size_t)(b * NKV_ + kh) * D_ + dt + dl) * S_ + st + sl] = tile[sl][dl];
  }
}

// ---------------------------------------------------------------------------
// Flash attention (S^T formulation): causal, GQA (kh = h/4), online softmax.
//  - XOR-swizzled, unpadded LDS tiles -> conflict-free ds_read_b128,
//    LDS = 40960 B -> 4 blocks/CU.
//  - K/V staged with global_load_lds width=16; swizzle via pre-swizzled
//    global source address (linear LDS dest, swizzled read).
//  - Q pre-scaled by 1/sqrt(D)*log2e -> exp2f, no per-score multiply.
//  - Causal mask only on the diagonal tile; defer-max (THR=8, log2 domain).
//  - qt reversed so heavy (long-loop) blocks launch first.
// ---------------------------------------------------------------------------
__global__ __launch_bounds__(256) void flash_attn(
    const bf16_t* __restrict__ Q, const bf16_t* __restrict__ K,
    const bf16_t* __restrict__ Vt, bf16_t* __restrict__ O) {
  const int qt = (S_ / 64 - 1) - blockIdx.x;  // heavy tiles first
  const int h  = blockIdx.y;   // 0..31
  const int b  = blockIdx.z;   // 0..1
  const int kh = h >> 2;
  const int tid = threadIdx.x, wave = tid >> 6, lane = tid & 63;
  const int lrow = lane & 15, quad = lane >> 4;
  const int q0 = qt * 64;

  // Physical LDS: linear rows, XOR-swizzled 16B slots within a row.
  __shared__ __align__(16) char lKb[64 * 256];   // K tile  [s][d], 256 B/row
  __shared__ __align__(16) char lVb[128 * 128];  // V^T tile [d][s], 128 B/row
  __shared__ __align__(16) char lPb[64 * 128];   // P tile  [q][s], 128 B/row

#define LK(r, c) (lKb + ((r) << 8) + ((c) ^ (((r) & 7) << 4)))
#define LV(r, c) (lVb + ((r) << 7) + ((c) ^ (((r) & 7) << 4)))
#define LP(r, c) (lPb + ((r) << 7) + ((c) ^ (((r) & 7) << 4)))

  const bf16_t* Qbase = Q  + ((size_t)(b * NQ_ + h) * S_) * D_;
  const bf16_t* Kbase = K  + ((size_t)(b * NKV_ + kh) * S_) * D_;
  const bf16_t* Vbase = Vt + ((size_t)(b * NKV_ + kh) * D_) * S_;

  // Q fragment (B-operand): lane holds Q[q=qrow][d=ks*32+quad*8+j]
  const int qrow = q0 + wave * 16 + lrow;
  bf16x8 qf[4];
  {
    const bf16_t* qp = Qbase + (size_t)qrow * D_ + quad * 8;
    for (int ks = 0; ks < 4; ++ks) qf[ks] = *(const bf16x8*)(qp + ks * 32);
  }

  const int krow = tid >> 4;                                        // 0..15
  const int kcol = ((((tid & 15) << 4)) ^ ((krow & 7) << 4)) >> 1;  // elems
  const int vrow = tid >> 3;                                        // 0..31
  const int vcol = ((((tid & 7) << 4)) ^ ((vrow & 7) << 4)) >> 1;   // elems

  floatx4 acc[8] = {};   // O^T[d = dt*16 + quad*4 + r][q = lrow]
  float mrun = -3.0e38f, lrun = 0.0f;

  const int nkt = qt + 1;
  for (int kt = 0; kt < nkt; ++kt) {
    const int k0 = kt * 64;
    __syncthreads();
#pragma unroll
    for (int i = 0; i < 4; ++i) {
      const bf16_t* ga = Kbase + (size_t)(k0 + i * 16 + krow) * D_ + kcol;
      __builtin_amdgcn_global_load_lds((GLOBAL_AS void*)ga,
          (LDS_AS void*)(lKb + i * 4096 + wave * 1024), 16, 0, 0);
    }
#pragma unroll
    for (int i = 0; i < 4; ++i) {
      const bf16_t* ga = Vbase + (size_t)(i * 32 + vrow) * S_ + k0 + vcol;
      __builtin_amdgcn_global_load_lds((GLOBAL_AS void*)ga,
          (LDS_AS void*)(lVb + i * 4096 + wave * 1024), 16, 0, 0);
    }
    __syncthreads();

    // S^T = K Q^T : lane holds S^T[k = k0 + t*16 + quad*4 + r][q = qrow].
    floatx4 sacc[4];
#pragma unroll
    for (int t = 0; t < 4; ++t) {
      floatx4 a = {0.f, 0.f, 0.f, 0.f};
#pragma unroll
      for (int ks = 0; ks < 4; ++ks) {
        bf16x8 kf = *(const bf16x8*)LK(t * 16 + lrow, ks * 64 + quad * 16);
        a = __builtin_amdgcn_mfma_f32_16x16x32_bf16(kf, qf[ks], a, 0, 0, 0);
      }
      sacc[t] = a;
    }

    if (kt == qt) {
#pragma unroll
      for (int t = 0; t < 4; ++t)
#pragma unroll
        for (int r = 0; r < 4; ++r) {
          const int kpos = k0 + t * 16 + quad * 4 + r;
          if (kpos > qrow) sacc[t][r] = -3.0e38f;
        }
    }

    float mx = -3.0e38f;
#pragma unroll
    for (int t = 0; t < 4; ++t)
#pragma unroll
      for (int r = 0; r < 4; ++r) mx = fmaxf(mx, sacc[t][r]);
    mx = fmaxf(mx, __shfl_xor(mx, 16));
    mx = fmaxf(mx, __shfl_xor(mx, 32));

    float mcur = mrun;
    if (!__all(mx - mrun <= 8.0f)) {
      const float mnew = fmaxf(mrun, mx);
      const float alpha = exp2f(mrun - mnew);
      lrun *= alpha;
#pragma unroll
      for (int dt = 0; dt < 8; ++dt) acc[dt] *= alpha;
      mrun = mnew;
      mcur = mnew;
    }

    float rs = 0.0f;
#pragma unroll
    for (int t = 0; t < 4; ++t) {
      bf16x4 pk;
#pragma unroll
      for (int r = 0; r < 4; ++r) {
        float p = exp2f(sacc[t][r] - mcur);
        rs += p;
        pk[r] = (bf16_t)p;
      }
      *(bf16x4*)LP(wave * 16 + lrow, t * 32 + quad * 8) = pk;
    }
    rs += __shfl_xor(rs, 16);
    rs += __shfl_xor(rs, 32);
    lrun += rs;

    bf16x8 pf0 = *(const bf16x8*)LP(wave * 16 + lrow, quad * 16);
    bf16x8 pf1 = *(const bf16x8*)LP(wave * 16 + lrow, 64 + quad * 16);
#pragma unroll
    for (int dt = 0; dt < 8; ++dt) {
      bf16x8 v0 = *(const bf16x8*)LV(dt * 16 + lrow, quad * 16);
      bf16x8 v1 = *(const bf16x8*)LV(dt * 16 + lrow, 64 + quad * 16);
      floatx4 a = acc[dt];
      a = __builtin_amdgcn_mfma_f32_16x16x32_bf16(v0, pf0, a, 0, 0, 0);
      a = __builtin_amdgcn_mfma_f32_16x16x32_bf16(v1, pf1, a, 0, 0, 0);
      acc[dt] = a;
    }
  }

  const float inv_l = 1.0f / lrun;
  bf16_t* Obase = O + ((size_t)(b * S_) + qrow) * (NQ_ * D_) + h * D_;
#pragma unroll
  for (int dt = 0; dt < 8; ++dt) {
    bf16x4 ov;
#pragma unroll
    for (int r = 0; r < 4; ++r) ov[r] = (bf16_t)(acc[dt][r] * inv_l);
    *(bf16x4*)(Obase + dt * 16 + quad * 4) = ov;
  }
#undef LK
#undef LV
#undef LP
}

// ---------------------------------------------------------------------------
// Launch
// ---------------------------------------------------------------------------
extern "C" void kernel_launch(void* const* d_in, const int* in_sizes, int n_in,
                              void* d_out, int out_size, void* d_ws, size_t ws_size,
                              hipStream_t stream) {
  const float* hs    = (const float*)d_in[0];   // [B,S,H] f32
  const float* w_qkv = (const float*)d_in[1];   // [H, 6144] f32
  const float* w_o   = (const float*)d_in[2];   // [4096, H] f32
  const int*   pos   = (const int*)d_in[3];     // [B,S]
  float* out = (float*)d_out;                   // [B,S,H] f32

  char* ws = (char*)d_ws;
  constexpr size_t OFF_WT  = 0;                         // 48 MB max
  constexpr size_t OFF_QKV = 50331648;                  // 48 MB
  constexpr size_t OFF_Q   = OFF_QKV + 50331648;        // 32 MB
  constexpr size_t OFF_K   = OFF_Q + 33554432;          // 8 MB
  constexpr size_t OFF_VT  = OFF_K + 8388608;           // 8 MB (end ~144 MB)
  bf16_t* wT    = (bf16_t*)(ws + OFF_WT);
  bf16_t* qkv   = (bf16_t*)(ws + OFF_QKV);
  bf16_t* Qb    = (bf16_t*)(ws + OFF_Q);
  bf16_t* Kb    = (bf16_t*)(ws + OFF_K);
  bf16_t* Vtb   = (bf16_t*)(ws + OFF_VT);
  bf16_t* hsb   = Qb;    // alias: hsb consumed by gemm1 before Q is written
  bf16_t* attnO = qkv;   // alias: qkv dead after rope/v_transpose

  // 0) hsb = bf16(hs)
  convert_f32_bf16<<<dim3((B_ * S_ * H_ / 4) / 256), 256, 0, stream>>>(
      hs, hsb, B_ * S_ * H_ / 4);
  // 1) wT = bf16(w_qkv^T)  [6144][4096]
  transpose_f32_bf16<<<dim3(NQKV_ / 64, H_ / 64), 256, 0, stream>>>(
      w_qkv, wT, H_, NQKV_);
  // 2) qkv = hsb @ w_qkv   (M=4096, N=6144, K=4096)
  gemm_abt256<bf16_t><<<dim3(NQKV_ / 256, (B_ * S_) / 256), 512, 0, stream>>>(
      hsb, wT, qkv, B_ * S_, NQKV_, H_);
  // 3) rope + q/k layout (overwrites hsb region with Q — hsb is dead now)
  rope_qk<<<dim3(B_ * S_), 256, 0, stream>>>(qkv, pos, Qb, Kb);
  // 4) v transpose
  v_transpose<<<dim3(S_ / 64, NKV_ * 2, B_), 256, 0, stream>>>(qkv, Vtb);
  // 5) wT = bf16(w_o^T)  [4096][4096]
  transpose_f32_bf16<<<dim3(H_ / 64, (NQ_ * D_) / 64), 256, 0, stream>>>(
      w_o, wT, NQ_ * D_, H_);
  // 6) attention -> attnO [B*S][4096]
  flash_attn<<<dim3(S_ / 64, NQ_, B_), 256, 0, stream>>>(Qb, Kb, Vtb, attnO);
  // 7) out = attnO @ w_o  (M=4096, N=4096, K=4096), f32 output
  gemm_abt256<float><<<dim3(H_ / 256, (B_ * S_) / 256), 512, 0, stream>>>(
      attnO, wT, out, B_ * S_, H_, H_);

  (void)in_sizes; (void)n_in; (void)out_size; (void)ws_size;
}

// Round 5
// 815.196 us; speedup vs baseline: 1.0319x; 1.0319x over previous
//
#include <hip/hip_runtime.h>
#include <hip/hip_bf16.h>
#include <stdint.h>

// Problem constants
#define B_  2
#define S_  2048
#define H_  4096
#define NQ_ 32
#define NKV_ 8
#define D_  128
#define NQKV_ 6144   // (NQ+2*NKV)*D

typedef __bf16 bf16_t;
typedef __bf16 bf16x4 __attribute__((ext_vector_type(4)));
typedef __bf16 bf16x8 __attribute__((ext_vector_type(8)));
typedef float  floatx4 __attribute__((ext_vector_type(4)));

#define GLOBAL_AS __attribute__((address_space(1)))
#define LDS_AS    __attribute__((address_space(3)))

// Softmax scale folded into Q at RoPE time: 1/sqrt(128) * log2(e)
#define QSCALE (0.08838834764831845f * 1.4426950408889634f)

// ---------------------------------------------------------------------------
// f32 -> bf16 elementwise convert (vectorized: 4 elems/thread)
// ---------------------------------------------------------------------------
__global__ __launch_bounds__(256) void convert_f32_bf16(
    const float* __restrict__ src, bf16_t* __restrict__ dst, int n4) {
  int i = blockIdx.x * 256 + threadIdx.x;
  if (i < n4) {
    float4 v = ((const float4*)src)[i];
    bf16_t o[4] = {(bf16_t)v.x, (bf16_t)v.y, (bf16_t)v.z, (bf16_t)v.w};
    ((uint64_t*)dst)[i] = *(const uint64_t*)o;
  }
}

// ---------------------------------------------------------------------------
// Transpose + convert: src f32 [R][C] -> dst bf16 [C][R], 64x64 LDS tiles
// ---------------------------------------------------------------------------
__global__ __launch_bounds__(256) void transpose_f32_bf16(
    const float* __restrict__ src, bf16_t* __restrict__ dst, int R, int C) {
  __shared__ bf16_t tile[64][65];
  const int ct = blockIdx.x * 64, rt = blockIdx.y * 64;
  const int t = threadIdx.x;
  const int cl = t & 63;
  for (int i = 0; i < 16; ++i) {
    int rl = i * 4 + (t >> 6);
    tile[rl][cl] = (bf16_t)src[(size_t)(rt + rl) * C + ct + cl];
  }
  __syncthreads();
  const int rl2 = t & 63;
  for (int i = 0; i < 16; ++i) {
    int cl2 = i * 4 + (t >> 6);
    dst[(size_t)(ct + cl2) * R + rt + rl2] = tile[rl2][cl2];
  }
}

// ---------------------------------------------------------------------------
// GEMM 256x256 (r2-proven): C[M,N] = A[M,K] * Bt[N,K]^T, flat counted-vmcnt
// pipeline: stage tile t+1 (8 loads/wave) before computing tile t, wait
// vmcnt(8), raw s_barrier pair, XOR-swizzled LDS, setprio, XCD swizzle.
// Requires M%256==0, N%256==0, K%64==0, nwg%8==0.
// ---------------------------------------------------------------------------
template <typename OutT>
__global__ __launch_bounds__(512, 2) void gemm_abt256(
    const bf16_t* __restrict__ A, const bf16_t* __restrict__ Bt,
    OutT* __restrict__ C, int M, int N, int K) {
  __shared__ __align__(16) char lds[131072];  // 2 bufs x (A 32K + B 32K)

  const int nbx = gridDim.x;
  const int nwg = nbx * gridDim.y;
  int bid = blockIdx.y * nbx + blockIdx.x;
  bid = (bid & 7) * (nwg >> 3) + (bid >> 3);
  const int bx = bid % nbx, by = bid / nbx;

  const int tid = threadIdx.x;               // 0..511
  const int wave = tid >> 6, lane = tid & 63;
  const int lrow = lane & 15, quad = lane >> 4;
  const int wm = (wave >> 2) * 128;          // wave M offset: 0/128
  const int wn = (wave & 3) * 64;            // wave N offset: 0/64/128/192
  const int row0 = by * 256, col0 = bx * 256;

  const int lr = lane >> 3;
  const int lc = ((((lane & 7) << 4) ^ (lr << 4)) >> 1);      // elem col

  auto stage = [&](int buf, int kt) {
    char* aB = lds + buf * 65536;
    char* bB = aB + 32768;
#pragma unroll
    for (int h = 0; h < 2; ++h)
#pragma unroll
      for (int i = 0; i < 2; ++i) {
        const bf16_t* ga =
            A + (size_t)(row0 + h * 128 + i * 64 + wave * 8 + lr) * K + kt + lc;
        __builtin_amdgcn_global_load_lds(
            (GLOBAL_AS void*)ga,
            (LDS_AS void*)(aB + h * 16384 + i * 8192 + wave * 1024), 16, 0, 0);
      }
#pragma unroll
    for (int h = 0; h < 2; ++h)
#pragma unroll
      for (int i = 0; i < 2; ++i) {
        const bf16_t* gb =
            Bt + (size_t)(col0 + h * 128 + i * 64 + wave * 8 + lr) * K + kt + lc;
        __builtin_amdgcn_global_load_lds(
            (GLOBAL_AS void*)gb,
            (LDS_AS void*)(bB + h * 16384 + i * 8192 + wave * 1024), 16, 0, 0);
      }
  };

  floatx4 acc[8][4] = {};
  const int nt = K >> 6;
  const int sw = (lrow & 7) << 4;  // read-side swizzle

  stage(0, 0);
  int cur = 0;
  for (int t = 0; t < nt; ++t) {
    if (t + 1 < nt) stage(cur ^ 1, (t + 1) * 64);  // 8 loads in flight
    __builtin_amdgcn_sched_barrier(0);
    if (t + 1 < nt)
      asm volatile("s_waitcnt vmcnt(8)" ::: "memory");  // tile t ready
    else
      asm volatile("s_waitcnt vmcnt(0)" ::: "memory");
    __builtin_amdgcn_s_barrier();
    __builtin_amdgcn_sched_barrier(0);

    const char* aB = lds + cur * 65536;
    const char* bB = aB + 32768;
    __builtin_amdgcn_s_setprio(1);
#pragma unroll
    for (int kk = 0; kk < 2; ++kk) {
      bf16x8 af[8], bfr[4];
#pragma unroll
      for (int fm = 0; fm < 8; ++fm) {
        const int r = wm + fm * 16 + lrow;
        af[fm] = *(const bf16x8*)(aB + r * 128 + ((kk * 64 + quad * 16) ^ sw));
      }
#pragma unroll
      for (int fn = 0; fn < 4; ++fn) {
        const int r = wn + fn * 16 + lrow;
        bfr[fn] = *(const bf16x8*)(bB + r * 128 + ((kk * 64 + quad * 16) ^ sw));
      }
#pragma unroll
      for (int fm = 0; fm < 8; ++fm)
#pragma unroll
        for (int fn = 0; fn < 4; ++fn)
          acc[fm][fn] = __builtin_amdgcn_mfma_f32_16x16x32_bf16(
              af[fm], bfr[fn], acc[fm][fn], 0, 0, 0);
    }
    __builtin_amdgcn_s_setprio(0);

    asm volatile("s_waitcnt lgkmcnt(0)" ::: "memory");  // reads done
    __builtin_amdgcn_s_barrier();                       // safe to overwrite
    __builtin_amdgcn_sched_barrier(0);
    cur ^= 1;
  }

  // epilogue: C/D layout col=lane&15, row=quad*4+reg
#pragma unroll
  for (int fm = 0; fm < 8; ++fm)
#pragma unroll
    for (int fn = 0; fn < 4; ++fn)
#pragma unroll
      for (int r = 0; r < 4; ++r) {
        int row = row0 + wm + fm * 16 + quad * 4 + r;
        int col = col0 + wn + fn * 16 + lrow;
        C[(size_t)row * N + col] = (OutT)acc[fm][fn][r];
      }
}

// ---------------------------------------------------------------------------
// GEMM 128x256: same r2 flat counted-vmcnt schedule, but tile 128(M)x256(N)
// so the QKV grid (M=4096,N=6144) is 32x24 = 768 blocks = exactly 3.0/CU
// (the 256^2 grid was 384 = 1.5/CU -> 25% idle tail, the measured QKV
// deficit vs the out-GEMM's perfect 256-block grid).
// 8 waves (2M x 4N), wave tile 64x64, acc 4x4. BK=64 double-buffered:
// LDS = 2 x (A 16K + B 32K) = 96 KiB. Per-wave staging: A 2 + B 4 = 6 loads
// per tile -> vmcnt(6). Same swizzle/barrier/setprio structure as above.
// Requires M%128==0, N%256==0, K%64==0, nwg%8==0.
// ---------------------------------------------------------------------------
template <typename OutT>
__global__ __launch_bounds__(512, 1) void gemm_abt128x256(
    const bf16_t* __restrict__ A, const bf16_t* __restrict__ Bt,
    OutT* __restrict__ C, int M, int N, int K) {
  __shared__ __align__(16) char lds[98304];  // 2 bufs x (A 16K + B 32K)

  const int nbx = gridDim.x;
  const int nwg = nbx * gridDim.y;
  int bid = blockIdx.y * nbx + blockIdx.x;
  bid = (bid & 7) * (nwg >> 3) + (bid >> 3);
  const int bx = bid % nbx, by = bid / nbx;

  const int tid = threadIdx.x;               // 0..511
  const int wave = tid >> 6, lane = tid & 63;
  const int lrow = lane & 15, quad = lane >> 4;
  const int wr = wave >> 2, wc = wave & 3;   // 2M x 4N wave grid
  const int row0 = by * 128, col0 = bx * 256;

  const int lr = lane >> 3;
  const int lc = ((((lane & 7) << 4) ^ (lr << 4)) >> 1);  // elem col

  // One buffer = A 16K (rows 0..127) + B 32K (rows 0..255), 128 B/row.
  auto stage = [&](char* buf, int kt) {
#pragma unroll
    for (int i = 0; i < 2; ++i) {
      const bf16_t* g =
          A + (size_t)(row0 + i * 64 + wave * 8 + lr) * K + kt + lc;
      __builtin_amdgcn_global_load_lds((GLOBAL_AS void*)g,
          (LDS_AS void*)(buf + i * 8192 + wave * 1024), 16, 0, 0);
    }
#pragma unroll
    for (int i = 0; i < 4; ++i) {
      const bf16_t* g =
          Bt + (size_t)(col0 + i * 64 + wave * 8 + lr) * K + kt + lc;
      __builtin_amdgcn_global_load_lds((GLOBAL_AS void*)g,
          (LDS_AS void*)(buf + 16384 + i * 8192 + wave * 1024), 16, 0, 0);
    }
  };

  floatx4 acc[4][4] = {};
  const int nt = K >> 6;
  const int sw = (lrow & 7) << 4;  // read-side swizzle

  stage(lds, 0);
  for (int t = 0; t < nt; ++t) {
    const int cur = t & 1;
    const char* buf = lds + cur * 49152;
    char* nbuf = lds + (cur ^ 1) * 49152;
    const bool pf = (t + 1 < nt);
    if (pf) stage(nbuf, (t + 1) * 64);  // 6 loads in flight
    __builtin_amdgcn_sched_barrier(0);
    if (pf) asm volatile("s_waitcnt vmcnt(6)" ::: "memory");
    else    asm volatile("s_waitcnt vmcnt(0)" ::: "memory");
    __builtin_amdgcn_s_barrier();
    __builtin_amdgcn_sched_barrier(0);

    const char* aB = buf;
    const char* bB = buf + 16384;
    bf16x8 af[4][2], bfr[4][2];
#pragma unroll
    for (int fm = 0; fm < 4; ++fm)
#pragma unroll
      for (int kk = 0; kk < 2; ++kk)
        af[fm][kk] = *(const bf16x8*)(aB + (wr * 64 + fm * 16 + lrow) * 128 +
                                      ((kk * 64 + quad * 16) ^ sw));
#pragma unroll
    for (int fn = 0; fn < 4; ++fn)
#pragma unroll
      for (int kk = 0; kk < 2; ++kk)
        bfr[fn][kk] = *(const bf16x8*)(bB + (wc * 64 + fn * 16 + lrow) * 128 +
                                       ((kk * 64 + quad * 16) ^ sw));
    __builtin_amdgcn_s_setprio(1);
#pragma unroll
    for (int kk = 0; kk < 2; ++kk)
#pragma unroll
      for (int fm = 0; fm < 4; ++fm)
#pragma unroll
        for (int fn = 0; fn < 4; ++fn)
          acc[fm][fn] = __builtin_amdgcn_mfma_f32_16x16x32_bf16(
              af[fm][kk], bfr[fn][kk], acc[fm][fn], 0, 0, 0);
    __builtin_amdgcn_s_setprio(0);

    asm volatile("s_waitcnt lgkmcnt(0)" ::: "memory");
    __builtin_amdgcn_s_barrier();
    __builtin_amdgcn_sched_barrier(0);
  }

  // epilogue: C/D layout col=lane&15, row=quad*4+reg
#pragma unroll
  for (int fm = 0; fm < 4; ++fm)
#pragma unroll
    for (int fn = 0; fn < 4; ++fn)
#pragma unroll
      for (int r = 0; r < 4; ++r) {
        int row = row0 + wr * 64 + fm * 16 + quad * 4 + r;
        int col = col0 + wc * 64 + fn * 16 + lrow;
        C[(size_t)row * N + col] = (OutT)acc[fm][fn][r];
      }
}

// ---------------------------------------------------------------------------
// RoPE (GPT-J interleaved) on q,k + layout transform
// qkv[B*S][6144] -> Q[B][NQ][S][D], K[B][NKV][S][D]
// Q additionally pre-scaled by 1/sqrt(D)*log2(e).
// ---------------------------------------------------------------------------
__global__ __launch_bounds__(256) void rope_qk(
    const bf16_t* __restrict__ qkv, const int* __restrict__ positions,
    bf16_t* __restrict__ Q, bf16_t* __restrict__ K) {
  const int row = blockIdx.x;                 // b*S + s
  const int b = row >> 11, s = row & (S_ - 1);
  const float pos = (float)positions[row];
  const bf16_t* src = qkv + (size_t)row * NQKV_;
  for (int p = threadIdx.x; p < (NQ_ + NKV_) * 64; p += 256) {
    const int head = p >> 6, i = p & 63;
    const float inv = __powf(10000.0f, -(float)i * (1.0f / 64.0f));
    const float f = pos * inv;
    const float cs = __cosf(f), sn = __sinf(f);
    const float x1 = (float)src[head * 128 + 2 * i];
    const float x2 = (float)src[head * 128 + 2 * i + 1];
    float o1 = x1 * cs - x2 * sn;
    float o2 = x2 * cs + x1 * sn;
    bf16_t* dst;
    if (head < NQ_) {
      o1 *= QSCALE;
      o2 *= QSCALE;
      dst = Q + ((size_t)(b * NQ_ + head) * S_ + s) * D_ + 2 * i;
    } else {
      dst = K + ((size_t)(b * NKV_ + (head - NQ_)) * S_ + s) * D_ + 2 * i;
    }
    dst[0] = (bf16_t)o1;
    dst[1] = (bf16_t)o2;
  }
}

// ---------------------------------------------------------------------------
// Extract V from qkv and transpose: qkv cols [5120,6144) -> Vt[B][NKV][D][S]
// ---------------------------------------------------------------------------
__global__ __launch_bounds__(256) void v_transpose(
    const bf16_t* __restrict__ qkv, bf16_t* __restrict__ Vt) {
  __shared__ bf16_t tile[64][65];
  const int b = blockIdx.z;
  const int kh = blockIdx.y >> 1;
  const int dt = (blockIdx.y & 1) * 64;
  const int st = blockIdx.x * 64;
  const int t = threadIdx.x;
  const int colbase = (NQ_ + NKV_) * D_ + kh * D_ + dt;  // 5120 + ...
  for (int i = 0; i < 16; ++i) {
    int sl = i * 4 + (t >> 6);
    int dl = t & 63;
    tile[sl][dl] = qkv[(size_t)(b * S_ + st + sl) * NQKV_ + colbase + dl];
  }
  __syncthreads();
  for (int i = 0; i < 16; ++i) {
    int dl = i * 4 + (t >> 6);
    int sl = t & 63;
    Vt[((size_t)(b * NKV_ + kh) * D_ + dt + dl) * S_ + st + sl] = tile[sl][dl];
  }
}

// ---------------------------------------------------------------------------
// Flash attention (S^T formulation): causal, GQA (kh = h/4), online softmax.
// (r2-proven version, unchanged)
// ---------------------------------------------------------------------------
__global__ __launch_bounds__(256) void flash_attn(
    const bf16_t* __restrict__ Q, const bf16_t* __restrict__ K,
    const bf16_t* __restrict__ Vt, bf16_t* __restrict__ O) {
  const int qt = (S_ / 64 - 1) - blockIdx.x;  // heavy tiles first
  const int h  = blockIdx.y;   // 0..31
  const int b  = blockIdx.z;   // 0..1
  const int kh = h >> 2;
  const int tid = threadIdx.x, wave = tid >> 6, lane = tid & 63;
  const int lrow = lane & 15, quad = lane >> 4;
  const int q0 = qt * 64;

  __shared__ __align__(16) char lKb[64 * 256];   // K tile  [s][d], 256 B/row
  __shared__ __align__(16) char lVb[128 * 128];  // V^T tile [d][s], 128 B/row
  __shared__ __align__(16) char lPb[64 * 128];   // P tile  [q][s], 128 B/row

#define LK(r, c) (lKb + ((r) << 8) + ((c) ^ (((r) & 7) << 4)))
#define LV(r, c) (lVb + ((r) << 7) + ((c) ^ (((r) & 7) << 4)))
#define LP(r, c) (lPb + ((r) << 7) + ((c) ^ (((r) & 7) << 4)))

  const bf16_t* Qbase = Q  + ((size_t)(b * NQ_ + h) * S_) * D_;
  const bf16_t* Kbase = K  + ((size_t)(b * NKV_ + kh) * S_) * D_;
  const bf16_t* Vbase = Vt + ((size_t)(b * NKV_ + kh) * D_) * S_;

  const int qrow = q0 + wave * 16 + lrow;
  bf16x8 qf[4];
  {
    const bf16_t* qp = Qbase + (size_t)qrow * D_ + quad * 8;
    for (int ks = 0; ks < 4; ++ks) qf[ks] = *(const bf16x8*)(qp + ks * 32);
  }

  const int krow = tid >> 4;                                        // 0..15
  const int kcol = ((((tid & 15) << 4)) ^ ((krow & 7) << 4)) >> 1;  // elems
  const int vrow = tid >> 3;                                        // 0..31
  const int vcol = ((((tid & 7) << 4)) ^ ((vrow & 7) << 4)) >> 1;   // elems

  floatx4 acc[8] = {};   // O^T[d = dt*16 + quad*4 + r][q = lrow]
  float mrun = -3.0e38f, lrun = 0.0f;

  const int nkt = qt + 1;
  for (int kt = 0; kt < nkt; ++kt) {
    const int k0 = kt * 64;
    __syncthreads();
#pragma unroll
    for (int i = 0; i < 4; ++i) {
      const bf16_t* ga = Kbase + (size_t)(k0 + i * 16 + krow) * D_ + kcol;
      __builtin_amdgcn_global_load_lds((GLOBAL_AS void*)ga,
          (LDS_AS void*)(lKb + i * 4096 + wave * 1024), 16, 0, 0);
    }
#pragma unroll
    for (int i = 0; i < 4; ++i) {
      const bf16_t* ga = Vbase + (size_t)(i * 32 + vrow) * S_ + k0 + vcol;
      __builtin_amdgcn_global_load_lds((GLOBAL_AS void*)ga,
          (LDS_AS void*)(lVb + i * 4096 + wave * 1024), 16, 0, 0);
    }
    __syncthreads();

    floatx4 sacc[4];
#pragma unroll
    for (int t = 0; t < 4; ++t) {
      floatx4 a = {0.f, 0.f, 0.f, 0.f};
#pragma unroll
      for (int ks = 0; ks < 4; ++ks) {
        bf16x8 kf = *(const bf16x8*)LK(t * 16 + lrow, ks * 64 + quad * 16);
        a = __builtin_amdgcn_mfma_f32_16x16x32_bf16(kf, qf[ks], a, 0, 0, 0);
      }
      sacc[t] = a;
    }

    if (kt == qt) {
#pragma unroll
      for (int t = 0; t < 4; ++t)
#pragma unroll
        for (int r = 0; r < 4; ++r) {
          const int kpos = k0 + t * 16 + quad * 4 + r;
          if (kpos > qrow) sacc[t][r] = -3.0e38f;
        }
    }

    float mx = -3.0e38f;
#pragma unroll
    for (int t = 0; t < 4; ++t)
#pragma unroll
      for (int r = 0; r < 4; ++r) mx = fmaxf(mx, sacc[t][r]);
    mx = fmaxf(mx, __shfl_xor(mx, 16));
    mx = fmaxf(mx, __shfl_xor(mx, 32));

    float mcur = mrun;
    if (!__all(mx - mrun <= 8.0f)) {
      const float mnew = fmaxf(mrun, mx);
      const float alpha = exp2f(mrun - mnew);
      lrun *= alpha;
#pragma unroll
      for (int dt = 0; dt < 8; ++dt) acc[dt] *= alpha;
      mrun = mnew;
      mcur = mnew;
    }

    float rs = 0.0f;
#pragma unroll
    for (int t = 0; t < 4; ++t) {
      bf16x4 pk;
#pragma unroll
      for (int r = 0; r < 4; ++r) {
        float p = exp2f(sacc[t][r] - mcur);
        rs += p;
        pk[r] = (bf16_t)p;
      }
      *(bf16x4*)LP(wave * 16 + lrow, t * 32 + quad * 8) = pk;
    }
    rs += __shfl_xor(rs, 16);
    rs += __shfl_xor(rs, 32);
    lrun += rs;

    bf16x8 pf0 = *(const bf16x8*)LP(wave * 16 + lrow, quad * 16);
    bf16x8 pf1 = *(const bf16x8*)LP(wave * 16 + lrow, 64 + quad * 16);
#pragma unroll
    for (int dt = 0; dt < 8; ++dt) {
      bf16x8 v0 = *(const bf16x8*)LV(dt * 16 + lrow, quad * 16);
      bf16x8 v1 = *(const bf16x8*)LV(dt * 16 + lrow, 64 + quad * 16);
      floatx4 a = acc[dt];
      a = __builtin_amdgcn_mfma_f32_16x16x32_bf16(v0, pf0, a, 0, 0, 0);
      a = __builtin_amdgcn_mfma_f32_16x16x32_bf16(v1, pf1, a, 0, 0, 0);
      acc[dt] = a;
    }
  }

  const float inv_l = 1.0f / lrun;
  bf16_t* Obase = O + ((size_t)(b * S_) + qrow) * (NQ_ * D_) + h * D_;
#pragma unroll
  for (int dt = 0; dt < 8; ++dt) {
    bf16x4 ov;
#pragma unroll
    for (int r = 0; r < 4; ++r) ov[r] = (bf16_t)(acc[dt][r] * inv_l);
    *(bf16x4*)(Obase + dt * 16 + quad * 4) = ov;
  }
#undef LK
#undef LV
#undef LP
}

// ---------------------------------------------------------------------------
// Launch
// ---------------------------------------------------------------------------
extern "C" void kernel_launch(void* const* d_in, const int* in_sizes, int n_in,
                              void* d_out, int out_size, void* d_ws, size_t ws_size,
                              hipStream_t stream) {
  const float* hs    = (const float*)d_in[0];   // [B,S,H] f32
  const float* w_qkv = (const float*)d_in[1];   // [H, 6144] f32
  const float* w_o   = (const float*)d_in[2];   // [4096, H] f32
  const int*   pos   = (const int*)d_in[3];     // [B,S]
  float* out = (float*)d_out;                   // [B,S,H] f32

  char* ws = (char*)d_ws;
  constexpr size_t OFF_WT  = 0;                         // 48 MB max
  constexpr size_t OFF_QKV = 50331648;                  // 48 MB
  constexpr size_t OFF_Q   = OFF_QKV + 50331648;        // 32 MB
  constexpr size_t OFF_K   = OFF_Q + 33554432;          // 8 MB
  constexpr size_t OFF_VT  = OFF_K + 8388608;           // 8 MB (end ~144 MB)
  bf16_t* wT    = (bf16_t*)(ws + OFF_WT);
  bf16_t* qkv   = (bf16_t*)(ws + OFF_QKV);
  bf16_t* Qb    = (bf16_t*)(ws + OFF_Q);
  bf16_t* Kb    = (bf16_t*)(ws + OFF_K);
  bf16_t* Vtb   = (bf16_t*)(ws + OFF_VT);
  bf16_t* hsb   = Qb;    // alias: hsb consumed by gemm1 before Q is written
  bf16_t* attnO = qkv;   // alias: qkv dead after rope/v_transpose

  // 0) hsb = bf16(hs)
  convert_f32_bf16<<<dim3((B_ * S_ * H_ / 4) / 256), 256, 0, stream>>>(
      hs, hsb, B_ * S_ * H_ / 4);
  // 1) wT = bf16(w_qkv^T)  [6144][4096]
  transpose_f32_bf16<<<dim3(NQKV_ / 64, H_ / 64), 256, 0, stream>>>(
      w_qkv, wT, H_, NQKV_);
  // 2) qkv = hsb @ w_qkv   (M=4096, N=6144, K=4096) — 128x256 tiles,
  //    grid 24x32 = 768 blocks = exactly 3 rounds of 256 CUs (no tail)
  gemm_abt128x256<bf16_t><<<dim3(NQKV_ / 256, (B_ * S_) / 128), 512, 0,
                            stream>>>(hsb, wT, qkv, B_ * S_, NQKV_, H_);
  // 3) rope + q/k layout (overwrites hsb region with Q — hsb is dead now)
  rope_qk<<<dim3(B_ * S_), 256, 0, stream>>>(qkv, pos, Qb, Kb);
  // 4) v transpose
  v_transpose<<<dim3(S_ / 64, NKV_ * 2, B_), 256, 0, stream>>>(qkv, Vtb);
  // 5) wT = bf16(w_o^T)  [4096][4096]
  transpose_f32_bf16<<<dim3(H_ / 64, (NQ_ * D_) / 64), 256, 0, stream>>>(
      w_o, wT, NQ_ * D_, H_);
  // 6) attention -> attnO [B*S][4096]
  flash_attn<<<dim3(S_ / 64, NQ_, B_), 256, 0, stream>>>(Qb, Kb, Vtb, attnO);
  // 7) out = attnO @ w_o  (M=4096, N=4096, K=4096), f32 output — 256x256,
  //    grid 16x16 = 256 blocks = exactly 1/CU (proven ~134 us)
  gemm_abt256<float><<<dim3(H_ / 256, (B_ * S_) / 256), 512, 0, stream>>>(
      attnO, wT, out, B_ * S_, H_, H_);

  (void)in_sizes; (void)n_in; (void)out_size; (void)ws_size;
}